// Round 4
// 595.799 us; speedup vs baseline: 1.1273x; 1.1273x over previous
//
#include <hip/hip_runtime.h>
#include <hip/hip_bf16.h>

typedef __bf16 bf16;
typedef __bf16 bf16x8 __attribute__((ext_vector_type(8)));
typedef float floatx4 __attribute__((ext_vector_type(4)));

#define MFMA_BF16(a, b, c) __builtin_amdgcn_mfma_f32_16x16x32_bf16((a), (b), (c), 0, 0, 0)

static constexpr int CH = 256;      // channels
static constexpr int NPIX = 9216;   // 96*96
static constexpr int MTOT = 2 * NPIX; // both batches, n-major rows
static constexpr int NQB = 72;      // 256-row attention q-blocks total (2 batches)

// async global->LDS, 16B per lane; LDS dest = wave-uniform base + lane*16
__device__ __forceinline__ void async16(void* lds, const void* g) {
  __builtin_amdgcn_global_load_lds(
      (const __attribute__((address_space(1))) void*)g,
      (__attribute__((address_space(3))) void*)lds, 16, 0, 0);
}

__device__ __forceinline__ unsigned short bfbits(float x) {
  bf16 h = (bf16)x;
  return __builtin_bit_cast(unsigned short, h);
}

// ---------------------------------------------------------------------------
// Weight split (fp32 -> bf16 hi/lo) + folded BN scale/bias
// ---------------------------------------------------------------------------
__global__ void prep_weights(const float* __restrict__ W,
                             const float* __restrict__ g, const float* __restrict__ b,
                             const float* __restrict__ m, const float* __restrict__ v,
                             bf16* __restrict__ Wh, bf16* __restrict__ Wl,
                             float* __restrict__ scale, float* __restrict__ bias) {
  int i = blockIdx.x * 256 + threadIdx.x;
  if (i < 6 * CH * CH) {
    float w = W[i];
    bf16 h = (bf16)w;
    Wh[i] = h;
    Wl[i] = (bf16)(w - (float)h);
  }
  if (i < 6 * CH) {
    float s = g[i] * rsqrtf(v[i] + 1e-5f);
    scale[i] = s;
    bias[i] = b[i] - m[i] * s;
  }
}

// ---------------------------------------------------------------------------
// Both inputs: fp32 [B][256][9216] (c-major) -> bf16 hi/lo [B*9216][256]
// bid < 1152 -> x, else fk
// ---------------------------------------------------------------------------
__global__ void split_transpose2(const float* __restrict__ xin, const float* __restrict__ fkin,
                                 bf16* __restrict__ ohx, bf16* __restrict__ olx,
                                 bf16* __restrict__ ohf, bf16* __restrict__ olf) {
  __shared__ float t[64][65];
  int bid = blockIdx.x;
  const float* in; bf16 *oh, *ol;
  if (bid >= 1152) { in = fkin; oh = ohf; ol = olf; bid -= 1152; }
  else             { in = xin;  oh = ohx; ol = olx; }
  int b = bid / 576, rem = bid % 576;
  int ct = rem / 144, nt = rem % 144;
  int c0 = ct * 64, n0 = nt * 64;
  int tid = threadIdx.x;
  int cr = tid >> 4, nc = (tid & 15) * 4;
  for (int rr = 0; rr < 64; rr += 16) {
    int c = cr + rr;
    const float* p = in + ((size_t)(b * CH + c0 + c) * NPIX) + n0 + nc;
    float4 val = *(const float4*)p;
    t[c][nc + 0] = val.x; t[c][nc + 1] = val.y;
    t[c][nc + 2] = val.z; t[c][nc + 3] = val.w;
  }
  __syncthreads();
  int n = tid >> 2, cb = (tid & 3) * 16;
  bf16 hb[16], lb[16];
#pragma unroll
  for (int j = 0; j < 16; j++) {
    float xv = t[cb + j][n];
    bf16 h = (bf16)xv;
    hb[j] = h;
    lb[j] = (bf16)(xv - (float)h);
  }
  size_t idx = (size_t)(b * NPIX + n0 + n) * CH + c0 + cb;
  *(bf16x8*)&oh[idx]     = *(bf16x8*)&hb[0];
  *(bf16x8*)&oh[idx + 8] = *(bf16x8*)&hb[8];
  *(bf16x8*)&ol[idx]     = *(bf16x8*)&lb[0];
  *(bf16x8*)&ol[idx + 8] = *(bf16x8*)&lb[8];
}

// ---------------------------------------------------------------------------
// bf16 [B*9216][256] (n-major) -> bf16 [B][256][9216] (c-major)   (for V)
// ---------------------------------------------------------------------------
__global__ void transpose_bf16(const bf16* __restrict__ in, bf16* __restrict__ out) {
  __shared__ bf16 t[64][72];
  int bid = blockIdx.x;
  int b = bid / 576, rem = bid % 576;
  int ct = rem / 144, nt = rem % 144;
  int c0 = ct * 64, n0 = nt * 64;
  int tid = threadIdx.x;
  int nr = tid >> 4, cc = (tid & 15) * 4;
  for (int rr = 0; rr < 64; rr += 16) {
    int n = nr + rr;
    const bf16* p = in + (size_t)(b * NPIX + n0 + n) * CH + c0 + cc;
#pragma unroll
    for (int j = 0; j < 4; j++) t[cc + j][n] = p[j];
  }
  __syncthreads();
  int c = tid >> 2, nb = (tid & 3) * 16;
  bf16 buf[16];
#pragma unroll
  for (int j = 0; j < 16; j++) buf[j] = t[c][nb + j];
  size_t idx = (size_t)(b * CH + c0 + c) * NPIX + n0 + nb;
  *(bf16x8*)&out[idx]     = *(bf16x8*)&buf[0];
  *(bf16x8*)&out[idx + 8] = *(bf16x8*)&buf[8];
}

// ---------------------------------------------------------------------------
// fp32 [B*9216][256] (n-major) -> fp32 [B][256][9216]   (final output)
// ---------------------------------------------------------------------------
__global__ void transpose_out(const float* __restrict__ in, float* __restrict__ out) {
  __shared__ float t[64][65];
  int bid = blockIdx.x;
  int b = bid / 576, rem = bid % 576;
  int ct = rem / 144, nt = rem % 144;
  int c0 = ct * 64, n0 = nt * 64;
  int tid = threadIdx.x;
  int nr = tid >> 4, cc = (tid & 15) * 4;
  for (int rr = 0; rr < 64; rr += 16) {
    int n = nr + rr;
    float4 v = *(const float4*)&in[(size_t)(b * NPIX + n0 + n) * CH + c0 + cc];
    t[cc + 0][n] = v.x; t[cc + 1][n] = v.y; t[cc + 2][n] = v.z; t[cc + 3][n] = v.w;
  }
  __syncthreads();
  int c = tid >> 2, nb = (tid & 3) * 16;
#pragma unroll
  for (int k = 0; k < 4; k++) {
    float4 o4 = make_float4(t[c][nb + 4 * k + 0], t[c][nb + 4 * k + 1],
                            t[c][nb + 4 * k + 2], t[c][nb + 4 * k + 3]);
    *(float4*)&out[(size_t)(b * CH + c0 + c) * NPIX + n0 + nb + 4 * k] = o4;
  }
}

// ---------------------------------------------------------------------------
// Batched split-bf16 conv-GEMM, 128x128 tiles (288 blocks per job).
// mode: 0 = write hi+lo bf16, 1 = hi only, 2 = fp32
// ---------------------------------------------------------------------------
struct ConvJob {
  const bf16 *Ah, *Al, *Bh, *Bl;
  const float *scale, *bias;
  bf16 *Yh, *Yl; float *Yf;
  int mode;
};

__global__ __launch_bounds__(256, 3) void conv128(ConvJob j0, ConvJob j1, ConvJob j2) {
  __shared__ bf16 lds[4][8 * 512];  // planes: Ah, Al, Bh, Bl
  int jid = blockIdx.x / 288;
  int bid = blockIdx.x % 288;
  ConvJob j = (jid == 0) ? j0 : (jid == 1) ? j1 : j2;

  int tid = threadIdx.x;
  int w = tid >> 6, l = tid & 63;
  int q = l >> 4, c16 = l & 15;
  int m0 = (bid >> 1) * 128;
  int o0 = (bid & 1) * 128;

  const bf16* src = (w == 0) ? j.Ah : (w == 1) ? j.Al : (w == 2) ? j.Bh : j.Bl;
  int rowbase = (w < 2) ? m0 : o0;
  const bf16* gp = src + (size_t)(rowbase + c16) * CH + q * 8;
  bf16* ldst = &lds[w][0];

  const floatx4 zero4 = {0.f, 0.f, 0.f, 0.f};
  floatx4 acc[4][4];
#pragma unroll
  for (int i = 0; i < 4; i++)
#pragma unroll
    for (int jj = 0; jj < 4; jj++) acc[i][jj] = zero4;

  int mo16 = (w & 1) * 4, no16 = (w >> 1) * 4;

  for (int k0 = 0; k0 < CH; k0 += 32) {
#pragma unroll
    for (int f = 0; f < 8; f++)
      async16(ldst + f * 512, gp + (size_t)f * 16 * CH + k0);
    __syncthreads();

    bf16x8 ah[4], al[4], bh[4], bl[4];
#pragma unroll
    for (int i = 0; i < 4; i++) {
      ah[i] = *(const bf16x8*)&lds[0][(mo16 + i) * 512 + l * 8];
      al[i] = *(const bf16x8*)&lds[1][(mo16 + i) * 512 + l * 8];
      bh[i] = *(const bf16x8*)&lds[2][(no16 + i) * 512 + l * 8];
      bl[i] = *(const bf16x8*)&lds[3][(no16 + i) * 512 + l * 8];
    }
#pragma unroll
    for (int i = 0; i < 4; i++)
#pragma unroll
      for (int jj = 0; jj < 4; jj++) {
        acc[i][jj] = MFMA_BF16(ah[i], bh[jj], acc[i][jj]);
        acc[i][jj] = MFMA_BF16(ah[i], bl[jj], acc[i][jj]);
        acc[i][jj] = MFMA_BF16(al[i], bh[jj], acc[i][jj]);
      }
    __syncthreads();
  }

  int mo = (w & 1) * 64, no = (w >> 1) * 64;
  float sc[4], bs[4];
#pragma unroll
  for (int jj = 0; jj < 4; jj++) {
    int o = o0 + no + 16 * jj + c16;
    sc[jj] = j.scale[o];
    bs[jj] = j.bias[o];
  }
#pragma unroll
  for (int i = 0; i < 4; i++) {
    int nrow = m0 + mo + 16 * i + 4 * q;
#pragma unroll
    for (int jj = 0; jj < 4; jj++) {
      int o = o0 + no + 16 * jj + c16;
#pragma unroll
      for (int r = 0; r < 4; r++) {
        float y = acc[i][jj][r] * sc[jj] + bs[jj];
        y = fmaxf(y, 0.f);
        size_t idx = (size_t)(nrow + r) * CH + o;
        if (j.mode == 2) {
          j.Yf[idx] = y;
        } else if (j.mode == 1) {
          j.Yh[idx] = (bf16)y;
        } else {
          bf16 h = (bf16)y;
          j.Yh[idx] = h;
          j.Yl[idx] = (bf16)(y - (float)h);
        }
      }
    }
  }
}

// ---------------------------------------------------------------------------
// 64x128-tile split-bf16 conv-GEMM, fp32 out (f_up). Grid 576, LDS 24 KB.
// ---------------------------------------------------------------------------
__global__ __launch_bounds__(256, 4) void conv64(
    const bf16* __restrict__ Ah, const bf16* __restrict__ Al,
    const bf16* __restrict__ Bh, const bf16* __restrict__ Bl,
    const float* __restrict__ scale, const float* __restrict__ bias,
    float* __restrict__ Yf) {
  __shared__ bf16 lds[24 * 512];  // flat frags: [Ah0-3, Al0-3, Bh0-7, Bl0-7]
  int tid = threadIdx.x;
  int w = tid >> 6, l = tid & 63;
  int q = l >> 4, c16 = l & 15;
  int m0 = (blockIdx.x >> 1) * 64;
  int o0 = (blockIdx.x & 1) * 128;

  const floatx4 zero4 = {0.f, 0.f, 0.f, 0.f};
  floatx4 acc[4][2];
#pragma unroll
  for (int i = 0; i < 4; i++) { acc[i][0] = zero4; acc[i][1] = zero4; }

  for (int k0 = 0; k0 < CH; k0 += 32) {
#pragma unroll
    for (int ff = 0; ff < 6; ff++) {
      int f = w * 6 + ff;
      const bf16* src; int rbase, fl;
      if (f < 4)       { src = Ah; rbase = m0; fl = f; }
      else if (f < 8)  { src = Al; rbase = m0; fl = f - 4; }
      else if (f < 16) { src = Bh; rbase = o0; fl = f - 8; }
      else             { src = Bl; rbase = o0; fl = f - 16; }
      async16(&lds[f * 512], src + (size_t)(rbase + fl * 16 + c16) * CH + k0 + q * 8);
    }
    __syncthreads();

    bf16x8 ah[4], al[4], bh[2], bl[2];
#pragma unroll
    for (int i = 0; i < 4; i++) {
      ah[i] = *(const bf16x8*)&lds[(0 + i) * 512 + l * 8];
      al[i] = *(const bf16x8*)&lds[(4 + i) * 512 + l * 8];
    }
#pragma unroll
    for (int n = 0; n < 2; n++) {
      bh[n] = *(const bf16x8*)&lds[(8 + 2 * w + n) * 512 + l * 8];
      bl[n] = *(const bf16x8*)&lds[(16 + 2 * w + n) * 512 + l * 8];
    }
#pragma unroll
    for (int i = 0; i < 4; i++)
#pragma unroll
      for (int n = 0; n < 2; n++) {
        acc[i][n] = MFMA_BF16(ah[i], bh[n], acc[i][n]);
        acc[i][n] = MFMA_BF16(ah[i], bl[n], acc[i][n]);
        acc[i][n] = MFMA_BF16(al[i], bh[n], acc[i][n]);
      }
    __syncthreads();
  }

  float sc[2], bs[2];
#pragma unroll
  for (int n = 0; n < 2; n++) {
    int o = o0 + 32 * w + 16 * n + c16;
    sc[n] = scale[o];
    bs[n] = bias[o];
  }
#pragma unroll
  for (int i = 0; i < 4; i++) {
    int nrow = m0 + 16 * i + 4 * q;
#pragma unroll
    for (int n = 0; n < 2; n++) {
      int o = o0 + 32 * w + 16 * n + c16;
#pragma unroll
      for (int r = 0; r < 4; r++) {
        float y = acc[i][n][r] * sc[n] + bs[n];
        Yf[(size_t)(nrow + r) * CH + o] = fmaxf(y, 0.f);
      }
    }
  }
}

// ---------------------------------------------------------------------------
// Split-KV flash attention partial, v2. BQ=256 (8 waves x 32 q-rows), BKV=32.
//
// DS-bandwidth redesign (prev kernel: 33 b128 reads per 32 MFMAs -> 17% MfmaUtil):
//  * 2 q-tiles per wave: every K-frag and V-frag ds_read_b128 feeds 2 MFMAs.
//  * swapped QK^T (mfma(K,Q)): C-layout col = q-row, so the key-axis softmax
//    reduce is 8 in-lane values + shfl_xor(16/32) -- no 4-step trees.
//  * P written as packed ds_write_b64 (4 bf16/lane), ~2-way conflicts.
//  * defer-max (THR=8): skip O-rescale + alpha broadcast unless tile max grows
//    by >8; P bounded by e^8, fine in fp32 accum + final normalization.
// VGPR: qf 64 + oacc 128 + transients ~ 230 -> 1 block/CU (8 waves, cap 256
// via __launch_bounds__(512,1)).
// LDS: 32K (K dbuf) + 32K (V dbuf) + 16K (P slabs) = 80 KB.
// ---------------------------------------------------------------------------
__global__ __launch_bounds__(512, 1) void attn_part(
    const bf16* __restrict__ Q, const bf16* __restrict__ K, const bf16* __restrict__ Vt,
    float* __restrict__ Opart, float* __restrict__ Mpart, float* __restrict__ Lpart,
    int niter) {
  __shared__ bf16 lK[2][16 * 512];  // 32 keys x 256 d, frag f = mt*8+kc
  __shared__ bf16 lV[2][16 * 512];  // 256 ch x 32 keys, frag ct = ch/16 (B-layout)
  __shared__ bf16 lP[16 * 512];     // per (wave,qt) 1KB slab: A-frag layout

  int tid = threadIdx.x;
  int w = tid >> 6, l = tid & 63;
  int q = l >> 4, c16 = l & 15;
  int bid = blockIdx.x;
  int qb = bid % NQB, s = bid / NQB;
  int b = qb / 36;
  int n0 = (qb % 36) * 256;
  int kv0 = s * niter * 32;
  size_t qkbase = (size_t)b * NPIX * CH;
  size_t vbase  = (size_t)b * CH * NPIX;

  // register-resident Q fragments (B-operand layout): rows n0+32w+16qt+c16
  bf16x8 qf[2][8];
#pragma unroll
  for (int qt = 0; qt < 2; qt++) {
    const bf16* qp = Q + qkbase + (size_t)(n0 + 32 * w + 16 * qt + c16) * CH + q * 8;
#pragma unroll
    for (int kc = 0; kc < 8; kc++) qf[qt][kc] = *(const bf16x8*)(qp + kc * 32);
  }

  const floatx4 zero4 = {0.f, 0.f, 0.f, 0.f};
  floatx4 oacc[2][16];  // [qt][ct]: rows 32w+16qt+(4q+r), ch 16ct+c16
#pragma unroll
  for (int qt = 0; qt < 2; qt++)
#pragma unroll
    for (int ct = 0; ct < 16; ct++) oacc[qt][ct] = zero4;
  float mrow[2] = {-1e30f, -1e30f};  // per-lane row = 16qt + c16
  float lrow[2] = {0.f, 0.f};

  // staging: waves 0-3 stage K (4 frags each), waves 4-7 stage V (4 frags each)
  bool kwave = (w < 4);
  const bf16* gp = kwave ? (K + qkbase + (size_t)kv0 * CH) : (Vt + vbase + kv0);
  size_t lbK = (size_t)c16 * CH + q * 8;
  size_t lbV = (size_t)c16 * NPIX + q * 8;

  auto stage = [&](int bi, const bf16* base) {
    if (kwave) {
#pragma unroll
      for (int ff = 0; ff < 4; ff++) {
        int f = 4 * w + ff, mt = f >> 3, kc = f & 7;
        async16(&lK[bi][f * 512], base + (size_t)(mt * 16) * CH + kc * 32 + lbK);
      }
    } else {
#pragma unroll
      for (int ff = 0; ff < 4; ff++) {
        int ct = (w - 4) * 4 + ff;
        async16(&lV[bi][ct * 512], base + (size_t)(ct * 16) * NPIX + lbV);
      }
    }
  };

  stage(0, gp);  // K(0), V(0); drained at first barrier

  for (int it = 0; it < niter; it++) {
    int cur = it & 1;
    __syncthreads();  // buffers `cur` ready; prev iter's reads retired

    if (it + 1 < niter) {
      gp += kwave ? 32 * CH : 32;
      stage(cur ^ 1, gp);
    }

    // S^T = K Q^T : sf[qt][mt], C col = q-row (c16), C row = key (4q+r)
    floatx4 sf[2][2] = {{zero4, zero4}, {zero4, zero4}};
#pragma unroll
    for (int kc = 0; kc < 8; kc++) {
      bf16x8 kf0 = *(const bf16x8*)&lK[cur][(0 * 8 + kc) * 512 + l * 8];
      bf16x8 kf1 = *(const bf16x8*)&lK[cur][(1 * 8 + kc) * 512 + l * 8];
      sf[0][0] = MFMA_BF16(kf0, qf[0][kc], sf[0][0]);
      sf[0][1] = MFMA_BF16(kf1, qf[0][kc], sf[0][1]);
      sf[1][0] = MFMA_BF16(kf0, qf[1][kc], sf[1][0]);
      sf[1][1] = MFMA_BF16(kf1, qf[1][kc], sf[1][1]);
    }

    // tile max per q-row: in-lane over 8 keys, then cross q-groups (xor16/32)
    float pm[2];
#pragma unroll
    for (int qt = 0; qt < 2; qt++) {
      float v0 = fmaxf(fmaxf(sf[qt][0][0], sf[qt][0][1]),
                       fmaxf(sf[qt][0][2], sf[qt][0][3]));
      float v1 = fmaxf(fmaxf(sf[qt][1][0], sf[qt][1][1]),
                       fmaxf(sf[qt][1][2], sf[qt][1][3]));
      float v2 = fmaxf(v0, v1);
      v2 = fmaxf(v2, __shfl_xor(v2, 16));
      v2 = fmaxf(v2, __shfl_xor(v2, 32));
      pm[qt] = v2;
    }

    // defer-max: only rescale when some row's max grew by > 8
    bool need = (pm[0] > mrow[0] + 8.f) | (pm[1] > mrow[1] + 8.f);
    if (__ballot((int)need) != 0ull) {
      float alpha[2];
#pragma unroll
      for (int qt = 0; qt < 2; qt++) {
        float mn = fmaxf(mrow[qt], pm[qt]);
        alpha[qt] = __expf(mrow[qt] - mn);
        mrow[qt] = mn;
        lrow[qt] *= alpha[qt];
      }
#pragma unroll
      for (int qt = 0; qt < 2; qt++) {
        // alpha lives at lane c16 == row; oacc rows are 4q+r -> shfl broadcast
        float a0 = __shfl(alpha[qt], 20 * q + 0);
        float a1 = __shfl(alpha[qt], 20 * q + 1);
        float a2 = __shfl(alpha[qt], 20 * q + 2);
        float a3 = __shfl(alpha[qt], 20 * q + 3);
#pragma unroll
        for (int ct = 0; ct < 16; ct++) {
          oacc[qt][ct][0] *= a0; oacc[qt][ct][1] *= a1;
          oacc[qt][ct][2] *= a2; oacc[qt][ct][3] *= a3;
        }
      }
    }

    // P = exp(S - m): pack 4 bf16 -> one b64 LDS write per (qt,mt); row sums
#pragma unroll
    for (int qt = 0; qt < 2; qt++) {
      float rs = 0.f;
#pragma unroll
      for (int mt = 0; mt < 2; mt++) {
        unsigned short u[4];
#pragma unroll
        for (int r = 0; r < 4; r++) {
          float pv = __expf(sf[qt][mt][r] - mrow[qt]);
          rs += pv;
          u[r] = bfbits(pv);
        }
        int k0 = 16 * mt + 4 * q;                         // this lane's 4 keys
        int e0 = (k0 >> 3) * 128 + (k0 & 7) + 8 * c16;    // A-frag elem index
        uint2 pk;
        pk.x = (unsigned)u[0] | ((unsigned)u[1] << 16);
        pk.y = (unsigned)u[2] | ((unsigned)u[3] << 16);
        *(uint2*)&lP[(2 * w + qt) * 512 + e0] = pk;
      }
      rs += __shfl_xor(rs, 16);
      rs += __shfl_xor(rs, 32);
      lrow[qt] += rs;
    }

    // PV: each V-frag read feeds both q-tiles (same-wave DS ordering for lP)
    bf16x8 pa0 = *(const bf16x8*)&lP[(2 * w + 0) * 512 + l * 8];
    bf16x8 pa1 = *(const bf16x8*)&lP[(2 * w + 1) * 512 + l * 8];
#pragma unroll
    for (int ct = 0; ct < 16; ct++) {
      bf16x8 vb = *(const bf16x8*)&lV[cur][ct * 512 + l * 8];
      oacc[0][ct] = MFMA_BF16(pa0, vb, oacc[0][ct]);
      oacc[1][ct] = MFMA_BF16(pa1, vb, oacc[1][ct]);
    }
  }

  // write partials (unnormalized O + m, l)
  if (q == 0) {
#pragma unroll
    for (int qt = 0; qt < 2; qt++) {
      int row = 32 * w + 16 * qt + c16;
      Mpart[(size_t)bid * 256 + row] = mrow[qt];
      Lpart[(size_t)bid * 256 + row] = lrow[qt];
    }
  }
  float* Ob = Opart + (size_t)bid * 256 * CH;
#pragma unroll
  for (int qt = 0; qt < 2; qt++)
#pragma unroll
    for (int ct = 0; ct < 16; ct++)
#pragma unroll
      for (int r = 0; r < 4; r++) {
        int row = 32 * w + 16 * qt + 4 * q + r;
        Ob[(size_t)row * CH + 16 * ct + c16] = oacc[qt][ct][r];
      }
}

// ---------------------------------------------------------------------------
// Combine S partials -> normalized O, split hi/lo bf16, n-major [MTOT][256]
// grid = NQB*4 (72 q-blocks x 4 row-quarters of 64 rows), 256 threads
// ---------------------------------------------------------------------------
__global__ __launch_bounds__(256) void attn_combine(
    const float* __restrict__ Opart, const float* __restrict__ Mpart,
    const float* __restrict__ Lpart,
    bf16* __restrict__ Oh, bf16* __restrict__ Ol, int S) {
  __shared__ float wgt[8][64];
  __shared__ float invl[64];
  int qb = blockIdx.x >> 2;
  int r0 = (blockIdx.x & 3) * 64;
  int t = threadIdx.x;
  if (t < 64) {
    int row = r0 + t;
    float m = -1e30f;
    for (int s = 0; s < S; s++)
      m = fmaxf(m, Mpart[(size_t)(s * NQB + qb) * 256 + row]);
    float lsum = 0.f;
    for (int s = 0; s < S; s++) {
      float wv = __expf(Mpart[(size_t)(s * NQB + qb) * 256 + row] - m);
      wgt[s][t] = wv;
      lsum += wv * Lpart[(size_t)(s * NQB + qb) * 256 + row];
    }
    invl[t] = 1.0f / lsum;
  }
  __syncthreads();
  int c = t;  // 256 threads = 256 channels
  for (int rr = 0; rr < 64; rr++) {
    int row = r0 + rr;
    float acc = 0.f;
    for (int s = 0; s < S; s++)
      acc += wgt[s][rr] * Opart[((size_t)(s * NQB + qb) * 256 + row) * CH + c];
    float y = acc * invl[rr];
    size_t idx = (size_t)(qb * 256 + row) * CH + c;
    bf16 h = (bf16)y;
    Oh[idx] = h;
    Ol[idx] = (bf16)(y - (float)h);
  }
}

// ---------------------------------------------------------------------------
extern "C" void kernel_launch(void* const* d_in, const int* in_sizes, int n_in,
                              void* d_out, int out_size, void* d_ws, size_t ws_size,
                              hipStream_t stream) {
  const float* x  = (const float*)d_in[0];
  const float* fk = (const float*)d_in[1];
  const float* Ws = (const float*)d_in[2];
  const float* g  = (const float*)d_in[3];
  const float* be = (const float*)d_in[4];
  const float* me = (const float*)d_in[5];
  const float* va = (const float*)d_in[6];
  float* out = (float*)d_out;

  char* p = (char*)d_ws;
  bf16* Wh = (bf16*)p; p += (size_t)6 * CH * CH * 2;
  bf16* Wl = (bf16*)p; p += (size_t)6 * CH * CH * 2;
  float* scale = (float*)p; p += (size_t)6 * CH * 4;
  float* bias  = (float*)p; p += (size_t)6 * CH * 4;
  size_t plane = (size_t)MTOT * CH * 2;  // 9,437,184 B per bf16 plane
  bf16* S0h = (bf16*)p; p += plane;
  bf16* S0l = (bf16*)p; p += plane;
  bf16* Qh  = (bf16*)p; p += plane;
  bf16* Kh  = (bf16*)p; p += plane;
  bf16* Vh  = (bf16*)p; p += plane;
  bf16* Vt  = (bf16*)p; p += plane;
  char* region = p;

  // Overlays inside `region` (all dead before attn_part writes Opart there):
  bf16* S2h = (bf16*)(region);              // fk transposed (hi)
  bf16* S2l = (bf16*)(region + plane);      // fk transposed (lo)
  bf16* P1h = (bf16*)(region + 2 * plane);  // psi1 out (hi)
  bf16* P1l = (bf16*)(region + 3 * plane);  // psi1 out (lo)
  bf16* F1h = (bf16*)(region + 4 * plane);  // phi1 out (hi)
  bf16* F1l = (bf16*)(region + 5 * plane);  // phi1 out (lo)

  size_t base_used = (size_t)(region - (char*)d_ws);
  size_t osz = (size_t)NQB * 256 * CH * 4;            // 18.9 MB per split
  size_t per_split = osz + 2 * (size_t)NQB * 256 * 4;
  long avail = (long)ws_size - (long)base_used;
  int S = 1;
  {
    int cand[5] = {8, 6, 4, 3, 2};
    for (int i = 0; i < 5; i++)
      if ((long)cand[i] * (long)per_split <= avail) { S = cand[i]; break; }
  }
  float* Opart = (float*)region;
  float* Mpart = (float*)(region + (size_t)S * osz);
  float* Lpart = Mpart + (size_t)S * NQB * 256;
  float* Y5 = (float*)region;  // f_up fp32 out, overlays Opart (dead after combine)

  (void)in_sizes; (void)n_in; (void)out_size;

  prep_weights<<<1536, 256, 0, stream>>>(Ws, g, be, me, va, Wh, Wl, scale, bias);
  split_transpose2<<<2304, 256, 0, stream>>>(x, fk, S0h, S0l, S2h, S2l);

  auto W = [&](int layer) { return Wh + (size_t)layer * CH * CH; };
  auto Wlo = [&](int layer) { return Wl + (size_t)layer * CH * CH; };

  ConvJob psi1  {S0h, S0l, W(0), Wlo(0), scale + 0 * CH, bias + 0 * CH, P1h, P1l, nullptr, 0};
  ConvJob phi1  {S2h, S2l, W(2), Wlo(2), scale + 2 * CH, bias + 2 * CH, F1h, F1l, nullptr, 0};
  ConvJob fdown {S2h, S2l, W(4), Wlo(4), scale + 4 * CH, bias + 4 * CH, Vh, nullptr, nullptr, 1};
  ConvJob psi2  {P1h, P1l, W(1), Wlo(1), scale + 1 * CH, bias + 1 * CH, Qh, nullptr, nullptr, 1};
  ConvJob phi2  {F1h, F1l, W(3), Wlo(3), scale + 3 * CH, bias + 3 * CH, Kh, nullptr, nullptr, 1};

  conv128<<<864, 256, 0, stream>>>(psi1, phi1, fdown);
  conv128<<<576, 256, 0, stream>>>(psi2, phi2, phi2);
  transpose_bf16<<<1152, 256, 0, stream>>>(Vh, Vt);
  attn_part<<<NQB * S, 512, 0, stream>>>(Qh, Kh, Vt, Opart, Mpart, Lpart, 288 / S);
  attn_combine<<<NQB * 4, 256, 0, stream>>>(Opart, Mpart, Lpart, S0h, S0l, S);
  conv64<<<576, 256, 0, stream>>>(S0h, S0l, W(5), Wlo(5), scale + 5 * CH, bias + 5 * CH, Y5);
  transpose_out<<<1152, 256, 0, stream>>>(Y5, out);
}

// Round 5
// 591.592 us; speedup vs baseline: 1.1353x; 1.0071x over previous
//
#include <hip/hip_runtime.h>
#include <hip/hip_bf16.h>

typedef __bf16 bf16;
typedef __bf16 bf16x8 __attribute__((ext_vector_type(8)));
typedef float floatx4 __attribute__((ext_vector_type(4)));
typedef float floatx16 __attribute__((ext_vector_type(16)));

#define MFMA_BF16(a, b, c) __builtin_amdgcn_mfma_f32_16x16x32_bf16((a), (b), (c), 0, 0, 0)
#define MFMA32(a, b, c) __builtin_amdgcn_mfma_f32_32x32x16_bf16((a), (b), (c), 0, 0, 0)

static constexpr int CH = 256;      // channels
static constexpr int NPIX = 9216;   // 96*96
static constexpr int MTOT = 2 * NPIX; // both batches, n-major rows
static constexpr int NQB2 = 144;    // 128-row attention q-blocks total (2 batches)

// async global->LDS, 16B per lane; LDS dest = wave-uniform base + lane*16
__device__ __forceinline__ void async16(void* lds, const void* g) {
  __builtin_amdgcn_global_load_lds(
      (const __attribute__((address_space(1))) void*)g,
      (__attribute__((address_space(3))) void*)lds, 16, 0, 0);
}

// pack two f32 -> one u32 of 2 bf16 (lo = first arg)
__device__ __forceinline__ unsigned cvtpk(float lo, float hi) {
  unsigned r;
  asm("v_cvt_pk_bf16_f32 %0, %1, %2" : "=v"(r) : "v"(lo), "v"(hi));
  return r;
}

// ---------------------------------------------------------------------------
// Weight split (fp32 -> bf16 hi/lo) + folded BN scale/bias
// ---------------------------------------------------------------------------
__global__ void prep_weights(const float* __restrict__ W,
                             const float* __restrict__ g, const float* __restrict__ b,
                             const float* __restrict__ m, const float* __restrict__ v,
                             bf16* __restrict__ Wh, bf16* __restrict__ Wl,
                             float* __restrict__ scale, float* __restrict__ bias) {
  int i = blockIdx.x * 256 + threadIdx.x;
  if (i < 6 * CH * CH) {
    float w = W[i];
    bf16 h = (bf16)w;
    Wh[i] = h;
    Wl[i] = (bf16)(w - (float)h);
  }
  if (i < 6 * CH) {
    float s = g[i] * rsqrtf(v[i] + 1e-5f);
    scale[i] = s;
    bias[i] = b[i] - m[i] * s;
  }
}

// ---------------------------------------------------------------------------
// Both inputs: fp32 [B][256][9216] (c-major) -> bf16 hi/lo [B*9216][256]
// bid < 1152 -> x, else fk
// ---------------------------------------------------------------------------
__global__ void split_transpose2(const float* __restrict__ xin, const float* __restrict__ fkin,
                                 bf16* __restrict__ ohx, bf16* __restrict__ olx,
                                 bf16* __restrict__ ohf, bf16* __restrict__ olf) {
  __shared__ float t[64][65];
  int bid = blockIdx.x;
  const float* in; bf16 *oh, *ol;
  if (bid >= 1152) { in = fkin; oh = ohf; ol = olf; bid -= 1152; }
  else             { in = xin;  oh = ohx; ol = olx; }
  int b = bid / 576, rem = bid % 576;
  int ct = rem / 144, nt = rem % 144;
  int c0 = ct * 64, n0 = nt * 64;
  int tid = threadIdx.x;
  int cr = tid >> 4, nc = (tid & 15) * 4;
  for (int rr = 0; rr < 64; rr += 16) {
    int c = cr + rr;
    const float* p = in + ((size_t)(b * CH + c0 + c) * NPIX) + n0 + nc;
    float4 val = *(const float4*)p;
    t[c][nc + 0] = val.x; t[c][nc + 1] = val.y;
    t[c][nc + 2] = val.z; t[c][nc + 3] = val.w;
  }
  __syncthreads();
  int n = tid >> 2, cb = (tid & 3) * 16;
  bf16 hb[16], lb[16];
#pragma unroll
  for (int j = 0; j < 16; j++) {
    float xv = t[cb + j][n];
    bf16 h = (bf16)xv;
    hb[j] = h;
    lb[j] = (bf16)(xv - (float)h);
  }
  size_t idx = (size_t)(b * NPIX + n0 + n) * CH + c0 + cb;
  *(bf16x8*)&oh[idx]     = *(bf16x8*)&hb[0];
  *(bf16x8*)&oh[idx + 8] = *(bf16x8*)&hb[8];
  *(bf16x8*)&ol[idx]     = *(bf16x8*)&lb[0];
  *(bf16x8*)&ol[idx + 8] = *(bf16x8*)&lb[8];
}

// ---------------------------------------------------------------------------
// bf16 [B*9216][256] (n-major) -> bf16 [B][256][9216] (c-major)   (for V)
// ---------------------------------------------------------------------------
__global__ void transpose_bf16(const bf16* __restrict__ in, bf16* __restrict__ out) {
  __shared__ bf16 t[64][72];
  int bid = blockIdx.x;
  int b = bid / 576, rem = bid % 576;
  int ct = rem / 144, nt = rem % 144;
  int c0 = ct * 64, n0 = nt * 64;
  int tid = threadIdx.x;
  int nr = tid >> 4, cc = (tid & 15) * 4;
  for (int rr = 0; rr < 64; rr += 16) {
    int n = nr + rr;
    const bf16* p = in + (size_t)(b * NPIX + n0 + n) * CH + c0 + cc;
#pragma unroll
    for (int j = 0; j < 4; j++) t[cc + j][n] = p[j];
  }
  __syncthreads();
  int c = tid >> 2, nb = (tid & 3) * 16;
  bf16 buf[16];
#pragma unroll
  for (int j = 0; j < 16; j++) buf[j] = t[c][nb + j];
  size_t idx = (size_t)(b * CH + c0 + c) * NPIX + n0 + nb;
  *(bf16x8*)&out[idx]     = *(bf16x8*)&buf[0];
  *(bf16x8*)&out[idx + 8] = *(bf16x8*)&buf[8];
}

// ---------------------------------------------------------------------------
// fp32 [B*9216][256] (n-major) -> fp32 [B][256][9216]   (final output)
// ---------------------------------------------------------------------------
__global__ void transpose_out(const float* __restrict__ in, float* __restrict__ out) {
  __shared__ float t[64][65];
  int bid = blockIdx.x;
  int b = bid / 576, rem = bid % 576;
  int ct = rem / 144, nt = rem % 144;
  int c0 = ct * 64, n0 = nt * 64;
  int tid = threadIdx.x;
  int nr = tid >> 4, cc = (tid & 15) * 4;
  for (int rr = 0; rr < 64; rr += 16) {
    int n = nr + rr;
    float4 v = *(const float4*)&in[(size_t)(b * NPIX + n0 + n) * CH + c0 + cc];
    t[cc + 0][n] = v.x; t[cc + 1][n] = v.y; t[cc + 2][n] = v.z; t[cc + 3][n] = v.w;
  }
  __syncthreads();
  int c = tid >> 2, nb = (tid & 3) * 16;
#pragma unroll
  for (int k = 0; k < 4; k++) {
    float4 o4 = make_float4(t[c][nb + 4 * k + 0], t[c][nb + 4 * k + 1],
                            t[c][nb + 4 * k + 2], t[c][nb + 4 * k + 3]);
    *(float4*)&out[(size_t)(b * CH + c0 + c) * NPIX + n0 + nb + 4 * k] = o4;
  }
}

// ---------------------------------------------------------------------------
// Batched split-bf16 conv-GEMM, 128x128 tiles (288 blocks per job).
// mode: 0 = write hi+lo bf16, 1 = hi only, 2 = fp32
// ---------------------------------------------------------------------------
struct ConvJob {
  const bf16 *Ah, *Al, *Bh, *Bl;
  const float *scale, *bias;
  bf16 *Yh, *Yl; float *Yf;
  int mode;
};

__global__ __launch_bounds__(256, 3) void conv128(ConvJob j0, ConvJob j1, ConvJob j2) {
  __shared__ bf16 lds[4][8 * 512];  // planes: Ah, Al, Bh, Bl
  int jid = blockIdx.x / 288;
  int bid = blockIdx.x % 288;
  ConvJob j = (jid == 0) ? j0 : (jid == 1) ? j1 : j2;

  int tid = threadIdx.x;
  int w = tid >> 6, l = tid & 63;
  int q = l >> 4, c16 = l & 15;
  int m0 = (bid >> 1) * 128;
  int o0 = (bid & 1) * 128;

  const bf16* src = (w == 0) ? j.Ah : (w == 1) ? j.Al : (w == 2) ? j.Bh : j.Bl;
  int rowbase = (w < 2) ? m0 : o0;
  const bf16* gp = src + (size_t)(rowbase + c16) * CH + q * 8;
  bf16* ldst = &lds[w][0];

  const floatx4 zero4 = {0.f, 0.f, 0.f, 0.f};
  floatx4 acc[4][4];
#pragma unroll
  for (int i = 0; i < 4; i++)
#pragma unroll
    for (int jj = 0; jj < 4; jj++) acc[i][jj] = zero4;

  int mo16 = (w & 1) * 4, no16 = (w >> 1) * 4;

  for (int k0 = 0; k0 < CH; k0 += 32) {
#pragma unroll
    for (int f = 0; f < 8; f++)
      async16(ldst + f * 512, gp + (size_t)f * 16 * CH + k0);
    __syncthreads();

    bf16x8 ah[4], al[4], bh[4], bl[4];
#pragma unroll
    for (int i = 0; i < 4; i++) {
      ah[i] = *(const bf16x8*)&lds[0][(mo16 + i) * 512 + l * 8];
      al[i] = *(const bf16x8*)&lds[1][(mo16 + i) * 512 + l * 8];
      bh[i] = *(const bf16x8*)&lds[2][(no16 + i) * 512 + l * 8];
      bl[i] = *(const bf16x8*)&lds[3][(no16 + i) * 512 + l * 8];
    }
#pragma unroll
    for (int i = 0; i < 4; i++)
#pragma unroll
      for (int jj = 0; jj < 4; jj++) {
        acc[i][jj] = MFMA_BF16(ah[i], bh[jj], acc[i][jj]);
        acc[i][jj] = MFMA_BF16(ah[i], bl[jj], acc[i][jj]);
        acc[i][jj] = MFMA_BF16(al[i], bh[jj], acc[i][jj]);
      }
    __syncthreads();
  }

  int mo = (w & 1) * 64, no = (w >> 1) * 64;
  float sc[4], bs[4];
#pragma unroll
  for (int jj = 0; jj < 4; jj++) {
    int o = o0 + no + 16 * jj + c16;
    sc[jj] = j.scale[o];
    bs[jj] = j.bias[o];
  }
#pragma unroll
  for (int i = 0; i < 4; i++) {
    int nrow = m0 + mo + 16 * i + 4 * q;
#pragma unroll
    for (int jj = 0; jj < 4; jj++) {
      int o = o0 + no + 16 * jj + c16;
#pragma unroll
      for (int r = 0; r < 4; r++) {
        float y = acc[i][jj][r] * sc[jj] + bs[jj];
        y = fmaxf(y, 0.f);
        size_t idx = (size_t)(nrow + r) * CH + o;
        if (j.mode == 2) {
          j.Yf[idx] = y;
        } else if (j.mode == 1) {
          j.Yh[idx] = (bf16)y;
        } else {
          bf16 h = (bf16)y;
          j.Yh[idx] = h;
          j.Yl[idx] = (bf16)(y - (float)h);
        }
      }
    }
  }
}

// ---------------------------------------------------------------------------
// 64x128-tile split-bf16 conv-GEMM, fp32 out (f_up). Grid 576, LDS 24 KB.
// ---------------------------------------------------------------------------
__global__ __launch_bounds__(256, 4) void conv64(
    const bf16* __restrict__ Ah, const bf16* __restrict__ Al,
    const bf16* __restrict__ Bh, const bf16* __restrict__ Bl,
    const float* __restrict__ scale, const float* __restrict__ bias,
    float* __restrict__ Yf) {
  __shared__ bf16 lds[24 * 512];  // flat frags: [Ah0-3, Al0-3, Bh0-7, Bl0-7]
  int tid = threadIdx.x;
  int w = tid >> 6, l = tid & 63;
  int q = l >> 4, c16 = l & 15;
  int m0 = (blockIdx.x >> 1) * 64;
  int o0 = (blockIdx.x & 1) * 128;

  const floatx4 zero4 = {0.f, 0.f, 0.f, 0.f};
  floatx4 acc[4][2];
#pragma unroll
  for (int i = 0; i < 4; i++) { acc[i][0] = zero4; acc[i][1] = zero4; }

  for (int k0 = 0; k0 < CH; k0 += 32) {
#pragma unroll
    for (int ff = 0; ff < 6; ff++) {
      int f = w * 6 + ff;
      const bf16* src; int rbase, fl;
      if (f < 4)       { src = Ah; rbase = m0; fl = f; }
      else if (f < 8)  { src = Al; rbase = m0; fl = f - 4; }
      else if (f < 16) { src = Bh; rbase = o0; fl = f - 8; }
      else             { src = Bl; rbase = o0; fl = f - 16; }
      async16(&lds[f * 512], src + (size_t)(rbase + fl * 16 + c16) * CH + k0 + q * 8);
    }
    __syncthreads();

    bf16x8 ah[4], al[4], bh[2], bl[2];
#pragma unroll
    for (int i = 0; i < 4; i++) {
      ah[i] = *(const bf16x8*)&lds[(0 + i) * 512 + l * 8];
      al[i] = *(const bf16x8*)&lds[(4 + i) * 512 + l * 8];
    }
#pragma unroll
    for (int n = 0; n < 2; n++) {
      bh[n] = *(const bf16x8*)&lds[(8 + 2 * w + n) * 512 + l * 8];
      bl[n] = *(const bf16x8*)&lds[(16 + 2 * w + n) * 512 + l * 8];
    }
#pragma unroll
    for (int i = 0; i < 4; i++)
#pragma unroll
      for (int n = 0; n < 2; n++) {
        acc[i][n] = MFMA_BF16(ah[i], bh[n], acc[i][n]);
        acc[i][n] = MFMA_BF16(ah[i], bl[n], acc[i][n]);
        acc[i][n] = MFMA_BF16(al[i], bh[n], acc[i][n]);
      }
    __syncthreads();
  }

  float sc[2], bs[2];
#pragma unroll
  for (int n = 0; n < 2; n++) {
    int o = o0 + 32 * w + 16 * n + c16;
    sc[n] = scale[o];
    bs[n] = bias[o];
  }
#pragma unroll
  for (int i = 0; i < 4; i++) {
    int nrow = m0 + 16 * i + 4 * q;
#pragma unroll
    for (int n = 0; n < 2; n++) {
      int o = o0 + 32 * w + 16 * n + c16;
#pragma unroll
      for (int r = 0; r < 4; r++) {
        float y = acc[i][n][r] * sc[n] + bs[n];
        Yf[(size_t)(nrow + r) * CH + o] = fmaxf(y, 0.f);
      }
    }
  }
}

// ---------------------------------------------------------------------------
// Split-KV flash attention partial, v3. BQ=128 (4 waves x 32 q-rows), BKV=32.
// 32x32x16 MFMAs, P fully in-register (no lP LDS round-trip).
//
// v2 post-mortem: both pipes <20%, occupancy 18% (one barrier-locked 8-wave
// block/CU) -> latency-bound, not throughput-bound. v3:
//  * 32x32x16 swapped QK (mfma(K,Q)): lane holds a whole q-row's 16 S values
//    (hi half in lane^32) -> row max/sum = in-lane tree + ONE shfl_xor(32).
//  * P -> PV A-frags via v_cvt_pk_bf16_f32 + shfl_xor(32) half-exchange
//    (direction-agnostic, unlike permlane32_swap). No lP, no lgkm P-wait.
//  * 256-thread blocks, LDS 64 KB, __launch_bounds__(256,2) -> 2 independent
//    blocks/CU; their phases de-synchronize and cover each other's bubbles.
//  * S=3 splits: grid 432 fully co-resident; Opart writes 151->57 MB.
// VGPR: qf 64 + oacc(AGPR) 128 + sf 32 transients -> fits 256/wave cap.
// ---------------------------------------------------------------------------
__global__ __launch_bounds__(256, 2) void attn_part(
    const bf16* __restrict__ Q, const bf16* __restrict__ K, const bf16* __restrict__ Vt,
    float* __restrict__ Opart, float* __restrict__ Mpart, float* __restrict__ Lpart,
    int niter) {
  __shared__ bf16 lK[2][16 * 512];  // frag ks: K[key=l&31][16ks+8hi+i]
  __shared__ bf16 lV[2][16 * 512];  // frag 2ct+ks2: V[ch=32ct+(l&31)][16ks2+8hi+i]

  int tid = threadIdx.x;
  int w = tid >> 6, l = tid & 63;
  int ql = l & 31, hi = l >> 5;
  int bid = blockIdx.x;
  int qb = bid % NQB2, s = bid / NQB2;
  int b = qb / 72;
  int n0 = (qb % 72) * 128;
  int kv0 = s * niter * 32;
  size_t qkbase = (size_t)b * NPIX * CH;
  size_t vbase  = (size_t)b * CH * NPIX;

  // Q fragments (B-operand 32x32x16): col = q-row = ql, k = 8hi+i per 16-ch step
  bf16x8 qf[16];
  {
    const bf16* qp = Q + qkbase + (size_t)(n0 + 32 * w + ql) * CH + 8 * hi;
#pragma unroll
    for (int ks = 0; ks < 16; ks++) qf[ks] = *(const bf16x8*)(qp + ks * 16);
  }

  floatx16 oacc[8];  // [ct]: O[q=(r&3)+8(r>>2)+4hi][ch=32ct+ql]
#pragma unroll
  for (int ct = 0; ct < 8; ct++)
#pragma unroll
    for (int r = 0; r < 16; r++) oacc[ct][r] = 0.f;
  float mrow = -1e30f, lrow = 0.f;

  const bf16* gK = K + qkbase + (size_t)kv0 * CH;
  const bf16* gV = Vt + vbase + kv0;

  // wave w stages K frags 4w..4w+3 and V frags 4w..4w+3 (8 async16/iter)
  auto stage = [&](int bi) {
#pragma unroll
    for (int ff = 0; ff < 4; ff++) {
      int f = 4 * w + ff;
      async16(&lK[bi][f * 512], gK + (size_t)ql * CH + f * 16 + 8 * hi);
      async16(&lV[bi][f * 512],
              gV + (size_t)((f >> 1) * 32 + ql) * NPIX + (f & 1) * 16 + 8 * hi);
    }
  };

  stage(0);

  for (int it = 0; it < niter; it++) {
    int cur = it & 1;
    __syncthreads();  // buffers `cur` ready (vmcnt drained); prev reads retired

    if (it + 1 < niter) {
      gK += 32 * CH; gV += 32;
      stage(cur ^ 1);
    }

    // S^T = K Q^T : D[key][q], two independent accumulator chains
    floatx16 sfA, sfB;
#pragma unroll
    for (int r = 0; r < 16; r++) { sfA[r] = 0.f; sfB[r] = 0.f; }
#pragma unroll
    for (int ks = 0; ks < 16; ks += 2) {
      bf16x8 kf0 = *(const bf16x8*)&lK[cur][(ks + 0) * 512 + l * 8];
      bf16x8 kf1 = *(const bf16x8*)&lK[cur][(ks + 1) * 512 + l * 8];
      sfA = MFMA32(kf0, qf[ks + 0], sfA);
      sfB = MFMA32(kf1, qf[ks + 1], sfB);
    }
    // combine + tile max for this lane's q-row (other 16 keys live in lane^32)
    float pm = -1e30f;
#pragma unroll
    for (int r = 0; r < 16; r++) {
      float sv = sfA[r] + sfB[r];
      sfA[r] = sv;
      pm = fmaxf(pm, sv);
    }
    pm = fmaxf(pm, __shfl_xor(pm, 32));

    // defer-max: rescale only when row max grew by > 8
    bool need = pm > mrow + 8.f;
    if (__ballot((int)need) != 0ull) {
      float mn = fmaxf(mrow, pm);
      float alpha = __expf(mrow - mn);
      mrow = mn;
      lrow *= alpha;
      float arow[16];
#pragma unroll
      for (int r = 0; r < 16; r++)
        arow[r] = __shfl(alpha, (r & 3) + 8 * (r >> 2) + 4 * hi);
#pragma unroll
      for (int ct = 0; ct < 8; ct++)
#pragma unroll
        for (int r = 0; r < 16; r++) oacc[ct][r] *= arow[r];
    }

    // P = exp(S - m) (all 16 values belong to this lane's own q-row)
    float p[16];
    float rs = 0.f;
#pragma unroll
    for (int r = 0; r < 16; r++) {
      p[r] = __expf(sfA[r] - mrow);
      rs += p[r];
    }
    rs += __shfl_xor(rs, 32);
    lrow += rs;

    // pack to PV A-frags: reg r holds key (r&3)+8(r>>2)+4hi
    // pk0..3 <- key groups A(4hi+0..3), B(8+4hi..), pk4..7 <- C(16+..), D(24+..)
    unsigned pk0 = cvtpk(p[0], p[1]),   pk1 = cvtpk(p[2], p[3]);
    unsigned pk2 = cvtpk(p[4], p[5]),   pk3 = cvtpk(p[6], p[7]);
    unsigned pk4 = cvtpk(p[8], p[9]),   pk5 = cvtpk(p[10], p[11]);
    unsigned pk6 = cvtpk(p[12], p[13]), pk7 = cvtpk(p[14], p[15]);
    // half-exchange with lane^32: frag word needs (own lo-group | partner's)
    unsigned z02 = hi ? pk0 : pk2; unsigned zx02 = __shfl_xor(z02, 32);
    unsigned z13 = hi ? pk1 : pk3; unsigned zx13 = __shfl_xor(z13, 32);
    unsigned z46 = hi ? pk4 : pk6; unsigned zx46 = __shfl_xor(z46, 32);
    unsigned z57 = hi ? pk5 : pk7; unsigned zx57 = __shfl_xor(z57, 32);
    uint4 u0, u1;
    u0.x = hi ? zx02 : pk0;  u0.y = hi ? zx13 : pk1;
    u0.z = hi ? pk2 : zx02;  u0.w = hi ? pk3 : zx13;
    u1.x = hi ? zx46 : pk4;  u1.y = hi ? zx57 : pk5;
    u1.z = hi ? pk6 : zx46;  u1.w = hi ? pk7 : zx57;
    bf16x8 pa0 = __builtin_bit_cast(bf16x8, u0);  // keys 0..15, k = 8hi+i
    bf16x8 pa1 = __builtin_bit_cast(bf16x8, u1);  // keys 16..31

    // PV: O[q][ch] += P[q][k] V[k][ch]
#pragma unroll
    for (int ct = 0; ct < 8; ct++) {
      bf16x8 vb0 = *(const bf16x8*)&lV[cur][(2 * ct + 0) * 512 + l * 8];
      bf16x8 vb1 = *(const bf16x8*)&lV[cur][(2 * ct + 1) * 512 + l * 8];
      oacc[ct] = MFMA32(pa0, vb0, oacc[ct]);
      oacc[ct] = MFMA32(pa1, vb1, oacc[ct]);
    }
  }

  // write partials (unnormalized O + m, l)
  if (hi == 0) {
    Mpart[(size_t)bid * 128 + 32 * w + ql] = mrow;
    Lpart[(size_t)bid * 128 + 32 * w + ql] = lrow;
  }
  float* Ob = Opart + (size_t)bid * 128 * CH;
#pragma unroll
  for (int ct = 0; ct < 8; ct++)
#pragma unroll
    for (int r = 0; r < 16; r++) {
      int row = 32 * w + (r & 3) + 8 * (r >> 2) + 4 * hi;
      Ob[(size_t)row * CH + 32 * ct + ql] = oacc[ct][r];
    }
}

// ---------------------------------------------------------------------------
// Combine S partials -> normalized O, split hi/lo bf16, n-major [MTOT][256]
// grid = NQB2 (144 q-blocks of 128 rows), 256 threads
// ---------------------------------------------------------------------------
__global__ __launch_bounds__(256) void attn_combine(
    const float* __restrict__ Opart, const float* __restrict__ Mpart,
    const float* __restrict__ Lpart,
    bf16* __restrict__ Oh, bf16* __restrict__ Ol, int S) {
  __shared__ float wgt[8][128];
  __shared__ float invl[128];
  int qb = blockIdx.x;
  int t = threadIdx.x;
  if (t < 128) {
    float m = -1e30f;
    for (int s = 0; s < S; s++)
      m = fmaxf(m, Mpart[(size_t)(s * NQB2 + qb) * 128 + t]);
    float lsum = 0.f;
    for (int s = 0; s < S; s++) {
      float wv = __expf(Mpart[(size_t)(s * NQB2 + qb) * 128 + t] - m);
      wgt[s][t] = wv;
      lsum += wv * Lpart[(size_t)(s * NQB2 + qb) * 128 + t];
    }
    invl[t] = 1.0f / lsum;
  }
  __syncthreads();
  int c = t;  // 256 threads = 256 channels
  for (int row = 0; row < 128; row++) {
    float acc = 0.f;
    for (int s = 0; s < S; s++)
      acc += wgt[s][row] * Opart[((size_t)(s * NQB2 + qb) * 128 + row) * CH + c];
    float y = acc * invl[row];
    size_t idx = (size_t)(qb * 128 + row) * CH + c;
    bf16 h = (bf16)y;
    Oh[idx] = h;
    Ol[idx] = (bf16)(y - (float)h);
  }
}

// ---------------------------------------------------------------------------
extern "C" void kernel_launch(void* const* d_in, const int* in_sizes, int n_in,
                              void* d_out, int out_size, void* d_ws, size_t ws_size,
                              hipStream_t stream) {
  const float* x  = (const float*)d_in[0];
  const float* fk = (const float*)d_in[1];
  const float* Ws = (const float*)d_in[2];
  const float* g  = (const float*)d_in[3];
  const float* be = (const float*)d_in[4];
  const float* me = (const float*)d_in[5];
  const float* va = (const float*)d_in[6];
  float* out = (float*)d_out;

  char* p = (char*)d_ws;
  bf16* Wh = (bf16*)p; p += (size_t)6 * CH * CH * 2;
  bf16* Wl = (bf16*)p; p += (size_t)6 * CH * CH * 2;
  float* scale = (float*)p; p += (size_t)6 * CH * 4;
  float* bias  = (float*)p; p += (size_t)6 * CH * 4;
  size_t plane = (size_t)MTOT * CH * 2;  // 9,437,184 B per bf16 plane
  bf16* S0h = (bf16*)p; p += plane;
  bf16* S0l = (bf16*)p; p += plane;
  bf16* Qh  = (bf16*)p; p += plane;
  bf16* Kh  = (bf16*)p; p += plane;
  bf16* Vh  = (bf16*)p; p += plane;
  bf16* Vt  = (bf16*)p; p += plane;
  char* region = p;

  // Overlays inside `region` (all dead before attn_part writes Opart there):
  bf16* S2h = (bf16*)(region);              // fk transposed (hi)
  bf16* S2l = (bf16*)(region + plane);      // fk transposed (lo)
  bf16* P1h = (bf16*)(region + 2 * plane);  // psi1 out (hi)
  bf16* P1l = (bf16*)(region + 3 * plane);  // psi1 out (lo)
  bf16* F1h = (bf16*)(region + 4 * plane);  // phi1 out (hi)
  bf16* F1l = (bf16*)(region + 5 * plane);  // phi1 out (lo)

  size_t base_used = (size_t)(region - (char*)d_ws);
  size_t osz = (size_t)NQB2 * 128 * CH * 4;           // 18.9 MB per split
  size_t per_split = osz + 2 * (size_t)NQB2 * 128 * 4;
  long avail = (long)ws_size - (long)base_used;
  int S = 1;
  {
    // S=3 -> grid 432 fully co-resident at 2 blocks/CU; 288 % S == 0 required
    int cand[3] = {3, 2, 1};
    for (int i = 0; i < 3; i++)
      if ((long)cand[i] * (long)per_split <= avail) { S = cand[i]; break; }
  }
  float* Opart = (float*)region;
  float* Mpart = (float*)(region + (size_t)S * osz);
  float* Lpart = Mpart + (size_t)S * NQB2 * 128;
  float* Y5 = (float*)region;  // f_up fp32 out, overlays Opart (dead after combine)

  (void)in_sizes; (void)n_in; (void)out_size;

  prep_weights<<<1536, 256, 0, stream>>>(Ws, g, be, me, va, Wh, Wl, scale, bias);
  split_transpose2<<<2304, 256, 0, stream>>>(x, fk, S0h, S0l, S2h, S2l);

  auto W = [&](int layer) { return Wh + (size_t)layer * CH * CH; };
  auto Wlo = [&](int layer) { return Wl + (size_t)layer * CH * CH; };

  ConvJob psi1  {S0h, S0l, W(0), Wlo(0), scale + 0 * CH, bias + 0 * CH, P1h, P1l, nullptr, 0};
  ConvJob phi1  {S2h, S2l, W(2), Wlo(2), scale + 2 * CH, bias + 2 * CH, F1h, F1l, nullptr, 0};
  ConvJob fdown {S2h, S2l, W(4), Wlo(4), scale + 4 * CH, bias + 4 * CH, Vh, nullptr, nullptr, 1};
  ConvJob psi2  {P1h, P1l, W(1), Wlo(1), scale + 1 * CH, bias + 1 * CH, Qh, nullptr, nullptr, 1};
  ConvJob phi2  {F1h, F1l, W(3), Wlo(3), scale + 3 * CH, bias + 3 * CH, Kh, nullptr, nullptr, 1};

  conv128<<<864, 256, 0, stream>>>(psi1, phi1, fdown);
  conv128<<<576, 256, 0, stream>>>(psi2, phi2, phi2);
  transpose_bf16<<<1152, 256, 0, stream>>>(Vh, Vt);
  attn_part<<<NQB2 * S, 256, 0, stream>>>(Qh, Kh, Vt, Opart, Mpart, Lpart, 288 / S);
  attn_combine<<<NQB2, 256, 0, stream>>>(Opart, Mpart, Lpart, S0h, S0l, S);
  conv64<<<576, 256, 0, stream>>>(S0h, S0l, W(5), Wlo(5), scale + 5 * CH, bias + 5 * CH, Y5);
  transpose_out<<<1152, 256, 0, stream>>>(Y5, out);
}